// Round 5
// baseline (53480.585 us; speedup 1.0000x reference)
//
#include <hip/hip_runtime.h>
#include <stdint.h>

namespace {

constexpr int cNI  = 50000;
constexpr int cNU  = 20000;
constexpr int cNT  = 50000;
constexpr int cNIM = 50000;
constexpr int cEB  = 400000;
constexpr int cETA = 200000;
constexpr int cEIA = 200000;
constexpr int cTOT = 3 * cNI;  // 150000 concatenated dst-count slots
constexpr int cSCANB = 37;     // ceil(150000/4096)

// strip counts (64 rows per strip)
constexpr int cSQ  = (cNI  + 63) / 64;   // 782
constexpr int cSU  = (cNU  + 63) / 64;   // 313
constexpr int cST  = (cNT  + 63) / 64;   // 782
constexpr int cSIM = (cNIM + 63) / 64;   // 782

typedef __bf16 bf16x8 __attribute__((ext_vector_type(8)));
typedef float  floatx4 __attribute__((ext_vector_type(4)));

__device__ __forceinline__ float bf2f(unsigned short u) {
  union { unsigned int i; float f; } c;
  c.i = ((unsigned int)u) << 16;
  return c.f;
}
__device__ __forceinline__ unsigned short f2bf(float f) {
  union { float f; unsigned int i; } c;
  c.f = f;
  unsigned int u = c.i;
  u += 0x7fffu + ((u >> 16) & 1u);  // round-to-nearest-even
  return (unsigned short)(u >> 16);
}
__device__ __forceinline__ float gelu_f(float x) {
  float u = 0.7978845608028654f * (x + 0.044715f * x * x * x);
  float e = __expf(2.f * u);
  float t = 1.f - 2.f / (e + 1.f);
  return 0.5f * x * (1.f + t);
}

// ---------------- combine weights: WkvT[512][256] = [Wka^T ; Wvm^T], p/sqrt(D) folded into Wka
__global__ __launch_bounds__(256) void combine_kernel(
    const float* __restrict__ Wk_u, const float* __restrict__ bk_u,
    const float* __restrict__ Wv_u, const float* __restrict__ bv_u,
    const float* __restrict__ Wk_t, const float* __restrict__ bk_t,
    const float* __restrict__ Wv_t, const float* __restrict__ bv_t,
    const float* __restrict__ Wk_i, const float* __restrict__ bk_i,
    const float* __restrict__ Wv_i, const float* __restrict__ bv_i,
    const float* __restrict__ a_b, const float* __restrict__ m_b, const float* __restrict__ p_b,
    const float* __restrict__ a_t, const float* __restrict__ m_t, const float* __restrict__ p_t,
    const float* __restrict__ a_i, const float* __restrict__ m_i, const float* __restrict__ p_i,
    const float* __restrict__ Wq, const float* __restrict__ bq,
    const float* __restrict__ Wo, const float* __restrict__ bo,
    unsigned short* __restrict__ WkvT_u, float* __restrict__ bkv_u,
    unsigned short* __restrict__ WkvT_t, float* __restrict__ bkv_t,
    unsigned short* __restrict__ WkvT_i, float* __restrict__ bkv_i,
    unsigned short* __restrict__ WqT, float* __restrict__ bqf,
    unsigned short* __restrict__ WoT, float* __restrict__ bof)
{
  int idx = blockIdx.x * 256 + threadIdx.x;
  if (idx < 3 * 512 * 256) {
    int rel  = idx >> 17;
    int rem  = idx & 131071;
    int jrow = rem >> 8;
    int k    = rem & 255;
    int isv  = jrow >> 8;
    int j = jrow & 255, h = j >> 5, e = j & 31;
    const float *W, *bin, *A, *pp;
    unsigned short* Wout; float* bout;
    if (rel == 0)      { W = isv ? Wv_u : Wk_u; bin = isv ? bv_u : bk_u; A = isv ? m_b : a_b; pp = p_b; Wout = WkvT_u; bout = bkv_u; }
    else if (rel == 1) { W = isv ? Wv_t : Wk_t; bin = isv ? bv_t : bk_t; A = isv ? m_t : a_t; pp = p_t; Wout = WkvT_t; bout = bkv_t; }
    else               { W = isv ? Wv_i : Wk_i; bin = isv ? bv_i : bk_i; A = isv ? m_i : a_i; pp = p_i; Wout = WkvT_i; bout = bkv_i; }
    float scale = isv ? 1.0f : pp[h] * 0.17677669529663687f;  // p[h]/sqrt(32)
    const float* wrow = W + k * 256 + h * 32;
    const float* acol = A + h * 1024 + e;
    float acc = 0.f;
    for (int d = 0; d < 32; ++d) acc += wrow[d] * acol[d * 32];
    Wout[jrow * 256 + k] = f2bf(acc * scale);
    if (k == 0) {
      const float* brow = bin + h * 32;
      float bacc = 0.f;
      for (int d = 0; d < 32; ++d) bacc += brow[d] * acol[d * 32];
      bout[jrow] = bacc * scale;
    }
  } else if (idx < 3 * 512 * 256 + 2 * 256 * 256) {
    int rem = idx - 3 * 512 * 256;
    int which = rem >> 16;
    int r2 = rem & 65535;
    int j = r2 >> 8, k = r2 & 255;
    if (which == 0) { WqT[j * 256 + k] = f2bf(Wq[k * 256 + j]); if (k == 0) bqf[j] = bq[j]; }
    else            { WoT[j * 256 + k] = f2bf(Wo[k * 256 + j]); if (k == 0) bof[j] = bo[j]; }
  }
}

// ---------------- strip GEMM v2: block owns 64 rows x full N.
// A fragments loaded DIRECTLY global->VGPR (64 regs, read once; no A LDS).
// B double-buffered in LDS as half-K (128) stages of a 64-col n-tile:
// 2 x [4][64][40] shorts = 40 KB total -> 4 blocks/CU. Per stage: prefetch
// next B into regs (loads in flight during MFMA), 16 MFMA, ds_write, 1 barrier.
// MODE 0: A f32 (inline cast), C bf16, 4-segment fused projection dispatch.
// MODE 1: A bf16, C f32 with skip/residual epilogue (N==256, single segment).
template <int MODE>
__global__ __launch_bounds__(256, 4) void gemm_strip_kernel(
    const void* __restrict__ A0, const unsigned short* __restrict__ B0,
    const float* __restrict__ bias0, void* __restrict__ C0, int M0, int N0,
    const void* __restrict__ A1, const unsigned short* __restrict__ B1,
    const float* __restrict__ bias1, void* __restrict__ C1, int M1, int N1,
    const void* __restrict__ A2, const unsigned short* __restrict__ B2,
    const float* __restrict__ bias2, void* __restrict__ C2, int M2, int N2,
    const void* __restrict__ A3, const unsigned short* __restrict__ B3,
    const float* __restrict__ bias3, void* __restrict__ C3, int M3, int N3,
    const float* __restrict__ xres, const float* __restrict__ skipp)
{
  __shared__ __align__(16) unsigned short Bs[2][4][64][40];

  const void* Avp; const unsigned short* BT; const float* bias; void* Cvp;
  int M, N, strip;
  int b = blockIdx.x;
  if (MODE == 1 || b < cSQ)            { Avp = A0; BT = B0; bias = bias0; Cvp = C0; M = M0; N = N0; strip = b; }
  else if (b < cSQ + cSU)              { Avp = A1; BT = B1; bias = bias1; Cvp = C1; M = M1; N = N1; strip = b - cSQ; }
  else if (b < cSQ + cSU + cST)        { Avp = A2; BT = B2; bias = bias2; Cvp = C2; M = M2; N = N2; strip = b - cSQ - cSU; }
  else                                 { Avp = A3; BT = B3; bias = bias3; Cvp = C3; M = M3; N = N3; strip = b - cSQ - cSU - cST; }

  const int tid = threadIdx.x;
  const int m0 = strip * 64;
  const int wave = tid >> 6, lane = tid & 63;
  const int wm = (wave >> 1) * 32, wn = (wave & 1) * 32;
  const int quad = lane >> 4, l16 = lane & 15;
  const int lrow = tid >> 2, lq = tid & 3;

  // ---- A fragments: global -> registers, read once (rows wm+l16 and wm+16+l16)
  bf16x8 af0[8], af1[8];
  {
    const int r0 = m0 + wm + l16;
    const int r1 = m0 + wm + 16 + l16;
#pragma unroll
    for (int kt = 0; kt < 8; ++kt) {
      union { uint4 u; bf16x8 v; } c0, c1;
      c0.u = make_uint4(0u, 0u, 0u, 0u);
      c1.u = make_uint4(0u, 0u, 0u, 0u);
      if (MODE == 0) {
        const float* Af = (const float*)Avp;
        if (r0 < M) {
          const float4* ap = (const float4*)(Af + (size_t)r0 * 256 + kt * 32 + quad * 8);
          float4 f0 = ap[0], f1 = ap[1];
          c0.u.x = (unsigned int)f2bf(f0.x) | ((unsigned int)f2bf(f0.y) << 16);
          c0.u.y = (unsigned int)f2bf(f0.z) | ((unsigned int)f2bf(f0.w) << 16);
          c0.u.z = (unsigned int)f2bf(f1.x) | ((unsigned int)f2bf(f1.y) << 16);
          c0.u.w = (unsigned int)f2bf(f1.z) | ((unsigned int)f2bf(f1.w) << 16);
        }
        if (r1 < M) {
          const float4* ap = (const float4*)(Af + (size_t)r1 * 256 + kt * 32 + quad * 8);
          float4 f0 = ap[0], f1 = ap[1];
          c1.u.x = (unsigned int)f2bf(f0.x) | ((unsigned int)f2bf(f0.y) << 16);
          c1.u.y = (unsigned int)f2bf(f0.z) | ((unsigned int)f2bf(f0.w) << 16);
          c1.u.z = (unsigned int)f2bf(f1.x) | ((unsigned int)f2bf(f1.y) << 16);
          c1.u.w = (unsigned int)f2bf(f1.z) | ((unsigned int)f2bf(f1.w) << 16);
        }
      } else {
        const unsigned short* Ab = (const unsigned short*)Avp;
        if (r0 < M) c0.u = *(const uint4*)(Ab + (size_t)r0 * 256 + kt * 32 + quad * 8);
        if (r1 < M) c1.u = *(const uint4*)(Ab + (size_t)r1 * 256 + kt * 32 + quad * 8);
      }
      af0[kt] = c0.v;
      af1[kt] = c1.v;
    }
  }

  float s = 0.f;
  if (MODE == 1) s = 1.f / (1.f + __expf(-skipp[0]));

  const int ntiles = N >> 6;
  const int nstages = ntiles * 2;  // (n-tile, k-half) pairs

  // stage loader: returns the 4 uint4 this thread stages for stage st
  auto load_stage = [&](int st, uint4* rv) {
#pragma unroll
    for (int kth = 0; kth < 4; ++kth) {
      int nt = st >> 1, kh = st & 1;
      rv[kth] = *(const uint4*)(BT + (size_t)((nt << 6) + lrow) * 256 + kh * 128 + kth * 32 + lq * 8);
    }
  };
  auto write_stage = [&](int buf, const uint4* rv) {
#pragma unroll
    for (int kth = 0; kth < 4; ++kth)
      *(uint4*)(&Bs[buf][kth][lrow][lq * 8]) = rv[kth];
  };

  // preload stage 0
  {
    uint4 rv[4];
    load_stage(0, rv);
    write_stage(0, rv);
  }
  __syncthreads();

  floatx4 acc00 = {0.f,0.f,0.f,0.f}, acc01 = {0.f,0.f,0.f,0.f};
  floatx4 acc10 = {0.f,0.f,0.f,0.f}, acc11 = {0.f,0.f,0.f,0.f};

  int buf = 0;
  for (int st = 0; st < nstages; ++st) {
    const int nt = st >> 1, kh = st & 1;
    // prefetch next stage (global loads in flight during MFMA below)
    uint4 nv[4];
    const bool more = (st + 1 < nstages);
    if (more) load_stage(st + 1, nv);

    // compute on Bs[buf]
#pragma unroll
    for (int kth = 0; kth < 4; ++kth) {
      bf16x8 b0 = *(const bf16x8*)(&Bs[buf][kth][wn + l16][quad * 8]);
      bf16x8 b1 = *(const bf16x8*)(&Bs[buf][kth][wn + 16 + l16][quad * 8]);
      const int ka = kh * 4 + kth;
      acc00 = __builtin_amdgcn_mfma_f32_16x16x32_bf16(af0[ka], b0, acc00, 0, 0, 0);
      acc01 = __builtin_amdgcn_mfma_f32_16x16x32_bf16(af0[ka], b1, acc01, 0, 0, 0);
      acc10 = __builtin_amdgcn_mfma_f32_16x16x32_bf16(af1[ka], b0, acc10, 0, 0, 0);
      acc11 = __builtin_amdgcn_mfma_f32_16x16x32_bf16(af1[ka], b1, acc11, 0, 0, 0);
    }

    if (kh == 1) {
      // epilogue for n-tile nt
      const int n0 = nt << 6;
      floatx4 accs[2][2] = {{acc00, acc01}, {acc10, acc11}};
#pragma unroll
      for (int mi = 0; mi < 2; ++mi) {
#pragma unroll
        for (int ni = 0; ni < 2; ++ni) {
          int col = n0 + wn + ni * 16 + l16;
          int rbase = m0 + wm + mi * 16 + quad * 4;
          float bcol = bias[col];
#pragma unroll
          for (int r = 0; r < 4; ++r) {
            int row = rbase + r;
            if (row < M) {
              float v = accs[mi][ni][r] + bcol;
              if (MODE == 0) {
                ((unsigned short*)Cvp)[(size_t)row * N + col] = f2bf(v);
              } else {
                float xi = xres[(size_t)row * 256 + col];
                float o = s * v + (1.f - s) * xi;
                ((float*)Cvp)[(size_t)row * 256 + col] = 0.5f * o + 0.5f * xi;
              }
            }
          }
        }
      }
      acc00 = {0.f,0.f,0.f,0.f}; acc01 = {0.f,0.f,0.f,0.f};
      acc10 = {0.f,0.f,0.f,0.f}; acc11 = {0.f,0.f,0.f,0.f};
    }

    if (more) write_stage(buf ^ 1, nv);
    __syncthreads();
    buf ^= 1;
  }
}

// ---------------- CSR build
__global__ __launch_bounds__(256) void hist_kernel(
    const int* __restrict__ ebd, const int* __restrict__ etd, const int* __restrict__ eid,
    int* __restrict__ cnt)
{
  int i = blockIdx.x * 256 + threadIdx.x;
  if (i < cEB)  atomicAdd(&cnt[ebd[i]], 1);
  if (i < cETA) atomicAdd(&cnt[cNI + etd[i]], 1);
  if (i < cEIA) atomicAdd(&cnt[2 * cNI + eid[i]], 1);
}

__global__ __launch_bounds__(256) void scan1_kernel(
    const int* __restrict__ cnt, int* __restrict__ tpre, int* __restrict__ bsum)
{
  __shared__ int wsum[4];
  const int tid = threadIdx.x, lane = tid & 63, wid = tid >> 6;
  const int base = blockIdx.x * 4096 + tid * 16;
  int s = 0;
  if (base + 16 <= cTOT) {
    const int4* p4 = (const int4*)(cnt + base);
    for (int j = 0; j < 4; ++j) { int4 v = p4[j]; s += v.x + v.y + v.z + v.w; }
  } else {
    for (int j = 0; j < 16; ++j) { int i = base + j; if (i < cTOT) s += cnt[i]; }
  }
  int x = s;
  for (int d = 1; d < 64; d <<= 1) { int t = __shfl_up(x, d, 64); if (lane >= d) x += t; }
  if (lane == 63) wsum[wid] = x;
  __syncthreads();
  int wb = 0;
  for (int w = 0; w < 4; ++w) { int v = wsum[w]; if (w < wid) wb += v; }
  tpre[blockIdx.x * 256 + tid] = wb + x - s;
  if (tid == 255) bsum[blockIdx.x] = wb + x;
}

// scan3 with inlined block-base reduction
__global__ __launch_bounds__(256) void scan3_kernel(
    const int* __restrict__ cnt, const int* __restrict__ tpre,
    const int* __restrict__ bsum, int* __restrict__ off, int* __restrict__ cur)
{
  const int tid = threadIdx.x;
  const int b = blockIdx.x;
  int bb = 0;
  for (int w = 0; w < b; ++w) bb += bsum[w];
  if (b == 0 && tid == 0) {
    off[cNI] = cEB;
    off[(cNI + 1) + cNI] = cETA;
    off[2 * (cNI + 1) + cNI] = cEIA;
  }
  const int base = b * 4096 + tid * 16;
  int run = bb + tpre[b * 256 + tid];
  for (int j = 0; j < 16; ++j) {
    int i = base + j;
    if (i >= cTOT) break;
    int rel = (i >= 2 * cNI) ? 2 : (i >= cNI ? 1 : 0);
    int pos = i - rel * cNI;
    int relbase = (rel == 0) ? 0 : (rel == 1) ? cEB : (cEB + cETA);
    int val = run - relbase;
    off[rel * (cNI + 1) + pos] = val;
    cur[rel * cNI + pos] = val;
    run += cnt[i];
  }
}

__global__ __launch_bounds__(256) void scatter_kernel(
    const int* __restrict__ ebs, const int* __restrict__ ebd,
    const int* __restrict__ ets, const int* __restrict__ etd,
    const int* __restrict__ eis, const int* __restrict__ eid,
    int* __restrict__ cur,
    int* __restrict__ ss_b, int* __restrict__ ss_t, int* __restrict__ ss_i)
{
  int i = blockIdx.x * 256 + threadIdx.x;
  if (i < cEB)  { int p = atomicAdd(&cur[ebd[i]], 1);           ss_b[p] = ebs[i]; }
  if (i < cETA) { int p = atomicAdd(&cur[cNI + etd[i]], 1);     ss_t[p] = ets[i]; }
  if (i < cEIA) { int p = atomicAdd(&cur[2 * cNI + eid[i]], 1); ss_i[p] = eis[i]; }
}

// ---------------- per-item attention: one wave per item, 4-edge unroll for MLP
__global__ __launch_bounds__(256) void attend_kernel(
    const unsigned short* __restrict__ q,
    const unsigned short* __restrict__ kv_u,
    const unsigned short* __restrict__ kv_t,
    const unsigned short* __restrict__ kv_i,
    const int* __restrict__ off,
    const int* __restrict__ ss_b, const int* __restrict__ ss_t, const int* __restrict__ ss_i,
    unsigned short* __restrict__ gout)
{
  const int wave = threadIdx.x >> 6;
  const int lane = threadIdx.x & 63;
  const int item = blockIdx.x * 4 + wave;
  if (item >= cNI) return;
  ushort4 qu = ((const ushort4*)(q + (size_t)item * 256))[lane];
  const float q0 = bf2f(qu.x), q1 = bf2f(qu.y), q2 = bf2f(qu.z), q3 = bf2f(qu.w);
  float t0 = 0.f, t1 = 0.f, t2 = 0.f, t3 = 0.f;

#define EDGE_DOT(ku, vu, den, a0, a1, a2, a3)                                \
  {                                                                          \
    float p = bf2f(ku.x) * q0 + bf2f(ku.y) * q1 +                            \
              bf2f(ku.z) * q2 + bf2f(ku.w) * q3;                             \
    p += __shfl_xor(p, 1, 8);                                                \
    p += __shfl_xor(p, 2, 8);                                                \
    p += __shfl_xor(p, 4, 8);                                                \
    p = fminf(fmaxf(p, -30.f), 30.f);                                        \
    float ex = __expf(p);                                                    \
    den += ex;                                                               \
    a0 += ex * bf2f(vu.x); a1 += ex * bf2f(vu.y);                            \
    a2 += ex * bf2f(vu.z); a3 += ex * bf2f(vu.w);                            \
  }

#define DO_REL(KV, OFFBASE, SS, NSRC)                                        \
  {                                                                          \
    int e0 = off[(OFFBASE) + item];                                          \
    int e1 = off[(OFFBASE) + item + 1];                                      \
    float den = 0.f, a0 = 0.f, a1 = 0.f, a2 = 0.f, a3 = 0.f;                 \
    int e = e0;                                                              \
    for (; e + 4 <= e1; e += 4) {                                            \
      int s0 = SS[e], s1 = SS[e + 1], s2 = SS[e + 2], s3 = SS[e + 3];        \
      if ((unsigned)s0 >= (unsigned)(NSRC)) s0 = 0;                          \
      if ((unsigned)s1 >= (unsigned)(NSRC)) s1 = 0;                          \
      if ((unsigned)s2 >= (unsigned)(NSRC)) s2 = 0;                          \
      if ((unsigned)s3 >= (unsigned)(NSRC)) s3 = 0;                          \
      const ushort4* p0 = (const ushort4*)((KV) + (size_t)s0 * 512);         \
      const ushort4* p1 = (const ushort4*)((KV) + (size_t)s1 * 512);         \
      const ushort4* p2 = (const ushort4*)((KV) + (size_t)s2 * 512);         \
      const ushort4* p3 = (const ushort4*)((KV) + (size_t)s3 * 512);         \
      ushort4 k0 = p0[lane], v0 = p0[64 + lane];                             \
      ushort4 k1 = p1[lane], v1 = p1[64 + lane];                             \
      ushort4 k2 = p2[lane], v2 = p2[64 + lane];                             \
      ushort4 k3 = p3[lane], v3 = p3[64 + lane];                             \
      EDGE_DOT(k0, v0, den, a0, a1, a2, a3)                                  \
      EDGE_DOT(k1, v1, den, a0, a1, a2, a3)                                  \
      EDGE_DOT(k2, v2, den, a0, a1, a2, a3)                                  \
      EDGE_DOT(k3, v3, den, a0, a1, a2, a3)                                  \
    }                                                                        \
    for (; e + 2 <= e1; e += 2) {                                            \
      int s0 = SS[e], s1 = SS[e + 1];                                        \
      if ((unsigned)s0 >= (unsigned)(NSRC)) s0 = 0;                          \
      if ((unsigned)s1 >= (unsigned)(NSRC)) s1 = 0;                          \
      const ushort4* p0 = (const ushort4*)((KV) + (size_t)s0 * 512);         \
      const ushort4* p1 = (const ushort4*)((KV) + (size_t)s1 * 512);         \
      ushort4 k0 = p0[lane], v0 = p0[64 + lane];                             \
      ushort4 k1 = p1[lane], v1 = p1[64 + lane];                             \
      EDGE_DOT(k0, v0, den, a0, a1, a2, a3)                                  \
      EDGE_DOT(k1, v1, den, a0, a1, a2, a3)                                  \
    }                                                                        \
    if (e < e1) {                                                            \
      int s0 = SS[e];                                                        \
      if ((unsigned)s0 >= (unsigned)(NSRC)) s0 = 0;                          \
      const ushort4* p0 = (const ushort4*)((KV) + (size_t)s0 * 512);         \
      ushort4 k0 = p0[lane], v0 = p0[64 + lane];                             \
      EDGE_DOT(k0, v0, den, a0, a1, a2, a3)                                  \
    }                                                                        \
    float inv = 1.f / (den + 1e-16f);                                        \
    t0 += a0 * inv; t1 += a1 * inv; t2 += a2 * inv; t3 += a3 * inv;          \
  }

  DO_REL(kv_u, 0, ss_b, cNU)
  DO_REL(kv_t, (cNI + 1), ss_t, cNT)
  DO_REL(kv_i, 2 * (cNI + 1), ss_i, cNIM)
#undef DO_REL
#undef EDGE_DOT

  ushort4 o;
  o.x = f2bf(gelu_f(t0));
  o.y = f2bf(gelu_f(t1));
  o.z = f2bf(gelu_f(t2));
  o.w = f2bf(gelu_f(t3));
  ((ushort4*)(gout + (size_t)item * 256))[lane] = o;
}

}  // namespace

extern "C" void kernel_launch(void* const* d_in, const int* in_sizes, int n_in,
                              void* d_out, int out_size, void* d_ws, size_t ws_size,
                              hipStream_t stream) {
  (void)in_sizes; (void)n_in; (void)out_size; (void)ws_size;
  const float* x_user  = (const float*)d_in[0];
  const float* x_item  = (const float*)d_in[1];
  const float* x_taste = (const float*)d_in[2];
  const float* x_image = (const float*)d_in[3];
  const int* eb_src  = (const int*)d_in[4];
  const int* eb_dst  = (const int*)d_in[5];
  const int* eta_src = (const int*)d_in[6];
  const int* eta_dst = (const int*)d_in[7];
  const int* eia_src = (const int*)d_in[8];
  const int* eia_dst = (const int*)d_in[9];
  const float* Wk_u = (const float*)d_in[10];
  const float* bk_u = (const float*)d_in[11];
  const float* Wv_u = (const float*)d_in[12];
  const float* bv_u = (const float*)d_in[13];
  const float* Wk_t = (const float*)d_in[14];
  const float* bk_t = (const float*)d_in[15];
  const float* Wv_t = (const float*)d_in[16];
  const float* bv_t = (const float*)d_in[17];
  const float* Wk_i = (const float*)d_in[18];
  const float* bk_i = (const float*)d_in[19];
  const float* Wv_i = (const float*)d_in[20];
  const float* bv_i = (const float*)d_in[21];
  const float* Wq   = (const float*)d_in[22];
  const float* bq   = (const float*)d_in[23];
  const float* a_b  = (const float*)d_in[24];
  const float* m_b  = (const float*)d_in[25];
  const float* p_b  = (const float*)d_in[26];
  const float* a_t  = (const float*)d_in[27];
  const float* m_t  = (const float*)d_in[28];
  const float* p_t  = (const float*)d_in[29];
  const float* a_i  = (const float*)d_in[30];
  const float* m_i  = (const float*)d_in[31];
  const float* p_i  = (const float*)d_in[32];
  const float* Wo   = (const float*)d_in[33];
  const float* bo   = (const float*)d_in[34];
  const float* skip = (const float*)d_in[35];

  char* p = (char*)d_ws;
  auto alloc = [&](size_t n) -> char* {
    char* r = p;
    p += (n + 255) & ~(size_t)255;
    return r;
  };
  unsigned short* q      = (unsigned short*)alloc((size_t)cNI * 256 * 2);
  unsigned short* kv_u   = (unsigned short*)alloc((size_t)cNU * 512 * 2);
  unsigned short* kv_t   = (unsigned short*)alloc((size_t)cNT * 512 * 2);
  unsigned short* kv_i   = (unsigned short*)alloc((size_t)cNIM * 512 * 2);
  unsigned short* gagg   = (unsigned short*)alloc((size_t)cNI * 256 * 2);
  unsigned short* WkvT_u = (unsigned short*)alloc(512 * 256 * 2);
  unsigned short* WkvT_t = (unsigned short*)alloc(512 * 256 * 2);
  unsigned short* WkvT_i = (unsigned short*)alloc(512 * 256 * 2);
  unsigned short* WqT    = (unsigned short*)alloc(256 * 256 * 2);
  unsigned short* WoT    = (unsigned short*)alloc(256 * 256 * 2);
  float* bkv_u = (float*)alloc(512 * 4);
  float* bkv_t = (float*)alloc(512 * 4);
  float* bkv_i = (float*)alloc(512 * 4);
  float* bqf   = (float*)alloc(256 * 4);
  float* bof   = (float*)alloc(256 * 4);
  int* cnt   = (int*)alloc((size_t)cTOT * 4);
  int* off   = (int*)alloc((size_t)3 * (cNI + 1) * 4);
  int* cur   = (int*)alloc((size_t)cTOT * 4);
  int* tpre  = (int*)alloc((size_t)cSCANB * 256 * 4);
  int* bsum  = (int*)alloc(64 * 4);
  int* ss_b = (int*)alloc((size_t)cEB * 4);
  int* ss_t = (int*)alloc((size_t)cETA * 4);
  int* ss_i = (int*)alloc((size_t)cEIA * 4);

  hipMemsetAsync(cnt, 0, (size_t)cTOT * 4, stream);

  combine_kernel<<<2048, 256, 0, stream>>>(
      Wk_u, bk_u, Wv_u, bv_u, Wk_t, bk_t, Wv_t, bv_t, Wk_i, bk_i, Wv_i, bv_i,
      a_b, m_b, p_b, a_t, m_t, p_t, a_i, m_i, p_i,
      Wq, bq, Wo, bo,
      WkvT_u, bkv_u, WkvT_t, bkv_t, WkvT_i, bkv_i, WqT, bqf, WoT, bof);

  // fused projection GEMMs: q | kv_u | kv_t | kv_i  (2659 strips)
  gemm_strip_kernel<0><<<cSQ + cSU + cST + cSIM, 256, 0, stream>>>(
      x_item,  WqT,    bqf,   q,    cNI,  256,
      x_user,  WkvT_u, bkv_u, kv_u, cNU,  512,
      x_taste, WkvT_t, bkv_t, kv_t, cNT,  512,
      x_image, WkvT_i, bkv_i, kv_i, cNIM, 512,
      nullptr, nullptr);

  hist_kernel<<<1563, 256, 0, stream>>>(eb_dst, eta_dst, eia_dst, cnt);
  scan1_kernel<<<cSCANB, 256, 0, stream>>>(cnt, tpre, bsum);
  scan3_kernel<<<cSCANB, 256, 0, stream>>>(cnt, tpre, bsum, off, cur);
  scatter_kernel<<<1563, 256, 0, stream>>>(eb_src, eb_dst, eta_src, eta_dst, eia_src, eia_dst,
                                           cur, ss_b, ss_t, ss_i);

  attend_kernel<<<12500, 256, 0, stream>>>(q, kv_u, kv_t, kv_i, off, ss_b, ss_t, ss_i, gagg);

  // final GEMM: A = gelu'd agg (bf16), epilogue does skip-blend + residual
  gemm_strip_kernel<1><<<cSQ, 256, 0, stream>>>(
      gagg, WoT, bof, d_out, cNI, 256,
      nullptr, nullptr, nullptr, nullptr, 0, 0,
      nullptr, nullptr, nullptr, nullptr, 0, 0,
      nullptr, nullptr, nullptr, nullptr, 0, 0,
      x_item, skip);
}

// Round 6
// 702.846 us; speedup vs baseline: 76.0915x; 76.0915x over previous
//
#include <hip/hip_runtime.h>
#include <stdint.h>

namespace {

constexpr int cNI  = 50000;
constexpr int cNU  = 20000;
constexpr int cNT  = 50000;
constexpr int cNIM = 50000;
constexpr int cEB  = 400000;
constexpr int cETA = 200000;
constexpr int cEIA = 200000;
constexpr int cTOT = 3 * cNI;  // 150000 concatenated dst-count slots
constexpr int cSCANB = 37;     // ceil(150000/4096)

// strip counts (64 rows per strip)
constexpr int cSQ  = (cNI  + 63) / 64;   // 782
constexpr int cSU  = (cNU  + 63) / 64;   // 313
constexpr int cST  = (cNT  + 63) / 64;   // 782
constexpr int cSIM = (cNIM + 63) / 64;   // 782

typedef __bf16 bf16x8 __attribute__((ext_vector_type(8)));
typedef float  floatx4 __attribute__((ext_vector_type(4)));

__device__ __forceinline__ float bf2f(unsigned short u) {
  union { unsigned int i; float f; } c;
  c.i = ((unsigned int)u) << 16;
  return c.f;
}
__device__ __forceinline__ unsigned short f2bf(float f) {
  union { float f; unsigned int i; } c;
  c.f = f;
  unsigned int u = c.i;
  u += 0x7fffu + ((u >> 16) & 1u);  // round-to-nearest-even
  return (unsigned short)(u >> 16);
}
__device__ __forceinline__ float gelu_f(float x) {
  float u = 0.7978845608028654f * (x + 0.044715f * x * x * x);
  float e = __expf(2.f * u);
  float t = 1.f - 2.f / (e + 1.f);
  return 0.5f * x * (1.f + t);
}

// ---------------- combine weights: WkvT[512][256] = [Wka^T ; Wvm^T], p/sqrt(D) folded into Wka
__global__ __launch_bounds__(256) void combine_kernel(
    const float* __restrict__ Wk_u, const float* __restrict__ bk_u,
    const float* __restrict__ Wv_u, const float* __restrict__ bv_u,
    const float* __restrict__ Wk_t, const float* __restrict__ bk_t,
    const float* __restrict__ Wv_t, const float* __restrict__ bv_t,
    const float* __restrict__ Wk_i, const float* __restrict__ bk_i,
    const float* __restrict__ Wv_i, const float* __restrict__ bv_i,
    const float* __restrict__ a_b, const float* __restrict__ m_b, const float* __restrict__ p_b,
    const float* __restrict__ a_t, const float* __restrict__ m_t, const float* __restrict__ p_t,
    const float* __restrict__ a_i, const float* __restrict__ m_i, const float* __restrict__ p_i,
    const float* __restrict__ Wq, const float* __restrict__ bq,
    const float* __restrict__ Wo, const float* __restrict__ bo,
    unsigned short* __restrict__ WkvT_u, float* __restrict__ bkv_u,
    unsigned short* __restrict__ WkvT_t, float* __restrict__ bkv_t,
    unsigned short* __restrict__ WkvT_i, float* __restrict__ bkv_i,
    unsigned short* __restrict__ WqT, float* __restrict__ bqf,
    unsigned short* __restrict__ WoT, float* __restrict__ bof)
{
  int idx = blockIdx.x * 256 + threadIdx.x;
  if (idx < 3 * 512 * 256) {
    int rel  = idx >> 17;
    int rem  = idx & 131071;
    int jrow = rem >> 8;
    int k    = rem & 255;
    int isv  = jrow >> 8;
    int j = jrow & 255, h = j >> 5, e = j & 31;
    const float *W, *bin, *A, *pp;
    unsigned short* Wout; float* bout;
    if (rel == 0)      { W = isv ? Wv_u : Wk_u; bin = isv ? bv_u : bk_u; A = isv ? m_b : a_b; pp = p_b; Wout = WkvT_u; bout = bkv_u; }
    else if (rel == 1) { W = isv ? Wv_t : Wk_t; bin = isv ? bv_t : bk_t; A = isv ? m_t : a_t; pp = p_t; Wout = WkvT_t; bout = bkv_t; }
    else               { W = isv ? Wv_i : Wk_i; bin = isv ? bv_i : bk_i; A = isv ? m_i : a_i; pp = p_i; Wout = WkvT_i; bout = bkv_i; }
    float scale = isv ? 1.0f : pp[h] * 0.17677669529663687f;  // p[h]/sqrt(32)
    const float* wrow = W + k * 256 + h * 32;
    const float* acol = A + h * 1024 + e;
    float acc = 0.f;
    for (int d = 0; d < 32; ++d) acc += wrow[d] * acol[d * 32];
    Wout[jrow * 256 + k] = f2bf(acc * scale);
    if (k == 0) {
      const float* brow = bin + h * 32;
      float bacc = 0.f;
      for (int d = 0; d < 32; ++d) bacc += brow[d] * acol[d * 32];
      bout[jrow] = bacc * scale;
    }
  } else if (idx < 3 * 512 * 256 + 2 * 256 * 256) {
    int rem = idx - 3 * 512 * 256;
    int which = rem >> 16;
    int r2 = rem & 65535;
    int j = r2 >> 8, k = r2 & 255;
    if (which == 0) { WqT[j * 256 + k] = f2bf(Wq[k * 256 + j]); if (k == 0) bqf[j] = bq[j]; }
    else            { WoT[j * 256 + k] = f2bf(Wo[k * 256 + j]); if (k == 0) bof[j] = bo[j]; }
  }
}

// ---------------- strip GEMM v3: block owns 64 rows x full N. ZERO LDS, ZERO barriers.
// A fragments global->VGPR once (64 regs). B fragments global->VGPR per n-tile in
// half-K groups of 8 loads (32 transient regs, 8-deep MLP); B is 256 KB L2-resident
// and wave-pair duplicates hit L1. No launch_bounds floor — r5 showed forcing
// occupancy on top of a 64-reg persistent array spills to scratch (110 GB fetch).
// MODE 0: A f32 (inline cast), C bf16, 4-segment fused projection dispatch.
// MODE 1: A bf16, C f32 with skip/residual epilogue (N==256, single segment).
template <int MODE>
__global__ __launch_bounds__(256) void gemm_strip_kernel(
    const void* __restrict__ A0, const unsigned short* __restrict__ B0,
    const float* __restrict__ bias0, void* __restrict__ C0, int M0, int N0,
    const void* __restrict__ A1, const unsigned short* __restrict__ B1,
    const float* __restrict__ bias1, void* __restrict__ C1, int M1, int N1,
    const void* __restrict__ A2, const unsigned short* __restrict__ B2,
    const float* __restrict__ bias2, void* __restrict__ C2, int M2, int N2,
    const void* __restrict__ A3, const unsigned short* __restrict__ B3,
    const float* __restrict__ bias3, void* __restrict__ C3, int M3, int N3,
    const float* __restrict__ xres, const float* __restrict__ skipp)
{
  const void* Avp; const unsigned short* BT; const float* bias; void* Cvp;
  int M, N, strip;
  int b = blockIdx.x;
  if (MODE == 1 || b < cSQ)            { Avp = A0; BT = B0; bias = bias0; Cvp = C0; M = M0; N = N0; strip = b; }
  else if (b < cSQ + cSU)              { Avp = A1; BT = B1; bias = bias1; Cvp = C1; M = M1; N = N1; strip = b - cSQ; }
  else if (b < cSQ + cSU + cST)        { Avp = A2; BT = B2; bias = bias2; Cvp = C2; M = M2; N = N2; strip = b - cSQ - cSU; }
  else                                 { Avp = A3; BT = B3; bias = bias3; Cvp = C3; M = M3; N = N3; strip = b - cSQ - cSU - cST; }

  const int tid = threadIdx.x;
  const int m0 = strip * 64;
  const int wave = tid >> 6, lane = tid & 63;
  const int wm = (wave >> 1) * 32, wn = (wave & 1) * 32;
  const int quad = lane >> 4, l16 = lane & 15;

  // ---- A fragments: global -> registers, read once (rows wm+l16, wm+16+l16)
  bf16x8 af0[8], af1[8];
  {
    const int r0 = m0 + wm + l16;
    const int r1 = m0 + wm + 16 + l16;
#pragma unroll
    for (int kt = 0; kt < 8; ++kt) {
      union { uint4 u; bf16x8 v; } c0, c1;
      c0.u = make_uint4(0u, 0u, 0u, 0u);
      c1.u = make_uint4(0u, 0u, 0u, 0u);
      if (MODE == 0) {
        const float* Af = (const float*)Avp;
        if (r0 < M) {
          const float4* ap = (const float4*)(Af + (size_t)r0 * 256 + kt * 32 + quad * 8);
          float4 f0 = ap[0], f1 = ap[1];
          c0.u.x = (unsigned int)f2bf(f0.x) | ((unsigned int)f2bf(f0.y) << 16);
          c0.u.y = (unsigned int)f2bf(f0.z) | ((unsigned int)f2bf(f0.w) << 16);
          c0.u.z = (unsigned int)f2bf(f1.x) | ((unsigned int)f2bf(f1.y) << 16);
          c0.u.w = (unsigned int)f2bf(f1.z) | ((unsigned int)f2bf(f1.w) << 16);
        }
        if (r1 < M) {
          const float4* ap = (const float4*)(Af + (size_t)r1 * 256 + kt * 32 + quad * 8);
          float4 f0 = ap[0], f1 = ap[1];
          c1.u.x = (unsigned int)f2bf(f0.x) | ((unsigned int)f2bf(f0.y) << 16);
          c1.u.y = (unsigned int)f2bf(f0.z) | ((unsigned int)f2bf(f0.w) << 16);
          c1.u.z = (unsigned int)f2bf(f1.x) | ((unsigned int)f2bf(f1.y) << 16);
          c1.u.w = (unsigned int)f2bf(f1.z) | ((unsigned int)f2bf(f1.w) << 16);
        }
      } else {
        const unsigned short* Ab = (const unsigned short*)Avp;
        if (r0 < M) c0.u = *(const uint4*)(Ab + (size_t)r0 * 256 + kt * 32 + quad * 8);
        if (r1 < M) c1.u = *(const uint4*)(Ab + (size_t)r1 * 256 + kt * 32 + quad * 8);
      }
      af0[kt] = c0.v;
      af1[kt] = c1.v;
    }
  }

  float s = 0.f;
  if (MODE == 1) s = 1.f / (1.f + __expf(-skipp[0]));

  const int ntiles = N >> 6;
  for (int nt = 0; nt < ntiles; ++nt) {
    const int n0 = nt << 6;
    const unsigned short* brow0 = BT + (size_t)(n0 + wn + l16) * 256 + quad * 8;
    const unsigned short* brow1 = BT + (size_t)(n0 + wn + 16 + l16) * 256 + quad * 8;

    floatx4 acc00 = {0.f,0.f,0.f,0.f}, acc01 = {0.f,0.f,0.f,0.f};
    floatx4 acc10 = {0.f,0.f,0.f,0.f}, acc11 = {0.f,0.f,0.f,0.f};

#pragma unroll
    for (int kh = 0; kh < 2; ++kh) {
      // 8 independent loads in flight, then 16 MFMA
      bf16x8 bf0[4], bf1[4];
#pragma unroll
      for (int kt = 0; kt < 4; ++kt) {
        bf0[kt] = *(const bf16x8*)(brow0 + kh * 128 + kt * 32);
        bf1[kt] = *(const bf16x8*)(brow1 + kh * 128 + kt * 32);
      }
#pragma unroll
      for (int kt = 0; kt < 4; ++kt) {
        const int ka = kh * 4 + kt;
        acc00 = __builtin_amdgcn_mfma_f32_16x16x32_bf16(af0[ka], bf0[kt], acc00, 0, 0, 0);
        acc01 = __builtin_amdgcn_mfma_f32_16x16x32_bf16(af0[ka], bf1[kt], acc01, 0, 0, 0);
        acc10 = __builtin_amdgcn_mfma_f32_16x16x32_bf16(af1[ka], bf0[kt], acc10, 0, 0, 0);
        acc11 = __builtin_amdgcn_mfma_f32_16x16x32_bf16(af1[ka], bf1[kt], acc11, 0, 0, 0);
      }
    }

    // epilogue for this n-tile
    floatx4 accs[2][2] = {{acc00, acc01}, {acc10, acc11}};
#pragma unroll
    for (int mi = 0; mi < 2; ++mi) {
#pragma unroll
      for (int ni = 0; ni < 2; ++ni) {
        int col = n0 + wn + ni * 16 + l16;
        int rbase = m0 + wm + mi * 16 + quad * 4;
        float bcol = bias[col];
#pragma unroll
        for (int r = 0; r < 4; ++r) {
          int row = rbase + r;
          if (row < M) {
            float v = accs[mi][ni][r] + bcol;
            if (MODE == 0) {
              ((unsigned short*)Cvp)[(size_t)row * N + col] = f2bf(v);
            } else {
              float xi = xres[(size_t)row * 256 + col];
              float o = s * v + (1.f - s) * xi;
              ((float*)Cvp)[(size_t)row * 256 + col] = 0.5f * o + 0.5f * xi;
            }
          }
        }
      }
    }
  }
}

// ---------------- CSR build
__global__ __launch_bounds__(256) void hist_kernel(
    const int* __restrict__ ebd, const int* __restrict__ etd, const int* __restrict__ eid,
    int* __restrict__ cnt)
{
  int i = blockIdx.x * 256 + threadIdx.x;
  if (i < cEB)  atomicAdd(&cnt[ebd[i]], 1);
  if (i < cETA) atomicAdd(&cnt[cNI + etd[i]], 1);
  if (i < cEIA) atomicAdd(&cnt[2 * cNI + eid[i]], 1);
}

__global__ __launch_bounds__(256) void scan1_kernel(
    const int* __restrict__ cnt, int* __restrict__ tpre, int* __restrict__ bsum)
{
  __shared__ int wsum[4];
  const int tid = threadIdx.x, lane = tid & 63, wid = tid >> 6;
  const int base = blockIdx.x * 4096 + tid * 16;
  int s = 0;
  if (base + 16 <= cTOT) {
    const int4* p4 = (const int4*)(cnt + base);
    for (int j = 0; j < 4; ++j) { int4 v = p4[j]; s += v.x + v.y + v.z + v.w; }
  } else {
    for (int j = 0; j < 16; ++j) { int i = base + j; if (i < cTOT) s += cnt[i]; }
  }
  int x = s;
  for (int d = 1; d < 64; d <<= 1) { int t = __shfl_up(x, d, 64); if (lane >= d) x += t; }
  if (lane == 63) wsum[wid] = x;
  __syncthreads();
  int wb = 0;
  for (int w = 0; w < 4; ++w) { int v = wsum[w]; if (w < wid) wb += v; }
  tpre[blockIdx.x * 256 + tid] = wb + x - s;
  if (tid == 255) bsum[blockIdx.x] = wb + x;
}

// scan3 with inlined block-base reduction
__global__ __launch_bounds__(256) void scan3_kernel(
    const int* __restrict__ cnt, const int* __restrict__ tpre,
    const int* __restrict__ bsum, int* __restrict__ off, int* __restrict__ cur)
{
  const int tid = threadIdx.x;
  const int b = blockIdx.x;
  int bb = 0;
  for (int w = 0; w < b; ++w) bb += bsum[w];
  if (b == 0 && tid == 0) {
    off[cNI] = cEB;
    off[(cNI + 1) + cNI] = cETA;
    off[2 * (cNI + 1) + cNI] = cEIA;
  }
  const int base = b * 4096 + tid * 16;
  int run = bb + tpre[b * 256 + tid];
  for (int j = 0; j < 16; ++j) {
    int i = base + j;
    if (i >= cTOT) break;
    int rel = (i >= 2 * cNI) ? 2 : (i >= cNI ? 1 : 0);
    int pos = i - rel * cNI;
    int relbase = (rel == 0) ? 0 : (rel == 1) ? cEB : (cEB + cETA);
    int val = run - relbase;
    off[rel * (cNI + 1) + pos] = val;
    cur[rel * cNI + pos] = val;
    run += cnt[i];
  }
}

__global__ __launch_bounds__(256) void scatter_kernel(
    const int* __restrict__ ebs, const int* __restrict__ ebd,
    const int* __restrict__ ets, const int* __restrict__ etd,
    const int* __restrict__ eis, const int* __restrict__ eid,
    int* __restrict__ cur,
    int* __restrict__ ss_b, int* __restrict__ ss_t, int* __restrict__ ss_i)
{
  int i = blockIdx.x * 256 + threadIdx.x;
  if (i < cEB)  { int p = atomicAdd(&cur[ebd[i]], 1);           ss_b[p] = ebs[i]; }
  if (i < cETA) { int p = atomicAdd(&cur[cNI + etd[i]], 1);     ss_t[p] = ets[i]; }
  if (i < cEIA) { int p = atomicAdd(&cur[2 * cNI + eid[i]], 1); ss_i[p] = eis[i]; }
}

// ---------------- per-item attention: one wave per item, 4-edge unroll for MLP
__global__ __launch_bounds__(256) void attend_kernel(
    const unsigned short* __restrict__ q,
    const unsigned short* __restrict__ kv_u,
    const unsigned short* __restrict__ kv_t,
    const unsigned short* __restrict__ kv_i,
    const int* __restrict__ off,
    const int* __restrict__ ss_b, const int* __restrict__ ss_t, const int* __restrict__ ss_i,
    unsigned short* __restrict__ gout)
{
  const int wave = threadIdx.x >> 6;
  const int lane = threadIdx.x & 63;
  const int item = blockIdx.x * 4 + wave;
  if (item >= cNI) return;
  ushort4 qu = ((const ushort4*)(q + (size_t)item * 256))[lane];
  const float q0 = bf2f(qu.x), q1 = bf2f(qu.y), q2 = bf2f(qu.z), q3 = bf2f(qu.w);
  float t0 = 0.f, t1 = 0.f, t2 = 0.f, t3 = 0.f;

#define EDGE_DOT(ku, vu, den, a0, a1, a2, a3)                                \
  {                                                                          \
    float p = bf2f(ku.x) * q0 + bf2f(ku.y) * q1 +                            \
              bf2f(ku.z) * q2 + bf2f(ku.w) * q3;                             \
    p += __shfl_xor(p, 1, 8);                                                \
    p += __shfl_xor(p, 2, 8);                                                \
    p += __shfl_xor(p, 4, 8);                                                \
    p = fminf(fmaxf(p, -30.f), 30.f);                                        \
    float ex = __expf(p);                                                    \
    den += ex;                                                               \
    a0 += ex * bf2f(vu.x); a1 += ex * bf2f(vu.y);                            \
    a2 += ex * bf2f(vu.z); a3 += ex * bf2f(vu.w);                            \
  }

#define DO_REL(KV, OFFBASE, SS, NSRC)                                        \
  {                                                                          \
    int e0 = off[(OFFBASE) + item];                                          \
    int e1 = off[(OFFBASE) + item + 1];                                      \
    float den = 0.f, a0 = 0.f, a1 = 0.f, a2 = 0.f, a3 = 0.f;                 \
    int e = e0;                                                              \
    for (; e + 4 <= e1; e += 4) {                                            \
      int s0 = SS[e], s1 = SS[e + 1], s2 = SS[e + 2], s3 = SS[e + 3];        \
      if ((unsigned)s0 >= (unsigned)(NSRC)) s0 = 0;                          \
      if ((unsigned)s1 >= (unsigned)(NSRC)) s1 = 0;                          \
      if ((unsigned)s2 >= (unsigned)(NSRC)) s2 = 0;                          \
      if ((unsigned)s3 >= (unsigned)(NSRC)) s3 = 0;                          \
      const ushort4* p0 = (const ushort4*)((KV) + (size_t)s0 * 512);         \
      const ushort4* p1 = (const ushort4*)((KV) + (size_t)s1 * 512);         \
      const ushort4* p2 = (const ushort4*)((KV) + (size_t)s2 * 512);         \
      const ushort4* p3 = (const ushort4*)((KV) + (size_t)s3 * 512);         \
      ushort4 k0 = p0[lane], v0 = p0[64 + lane];                             \
      ushort4 k1 = p1[lane], v1 = p1[64 + lane];                             \
      ushort4 k2 = p2[lane], v2 = p2[64 + lane];                             \
      ushort4 k3 = p3[lane], v3 = p3[64 + lane];                             \
      EDGE_DOT(k0, v0, den, a0, a1, a2, a3)                                  \
      EDGE_DOT(k1, v1, den, a0, a1, a2, a3)                                  \
      EDGE_DOT(k2, v2, den, a0, a1, a2, a3)                                  \
      EDGE_DOT(k3, v3, den, a0, a1, a2, a3)                                  \
    }                                                                        \
    for (; e + 2 <= e1; e += 2) {                                            \
      int s0 = SS[e], s1 = SS[e + 1];                                        \
      if ((unsigned)s0 >= (unsigned)(NSRC)) s0 = 0;                          \
      if ((unsigned)s1 >= (unsigned)(NSRC)) s1 = 0;                          \
      const ushort4* p0 = (const ushort4*)((KV) + (size_t)s0 * 512);         \
      const ushort4* p1 = (const ushort4*)((KV) + (size_t)s1 * 512);         \
      ushort4 k0 = p0[lane], v0 = p0[64 + lane];                             \
      ushort4 k1 = p1[lane], v1 = p1[64 + lane];                             \
      EDGE_DOT(k0, v0, den, a0, a1, a2, a3)                                  \
      EDGE_DOT(k1, v1, den, a0, a1, a2, a3)                                  \
    }                                                                        \
    if (e < e1) {                                                            \
      int s0 = SS[e];                                                        \
      if ((unsigned)s0 >= (unsigned)(NSRC)) s0 = 0;                          \
      const ushort4* p0 = (const ushort4*)((KV) + (size_t)s0 * 512);         \
      ushort4 k0 = p0[lane], v0 = p0[64 + lane];                             \
      EDGE_DOT(k0, v0, den, a0, a1, a2, a3)                                  \
    }                                                                        \
    float inv = 1.f / (den + 1e-16f);                                        \
    t0 += a0 * inv; t1 += a1 * inv; t2 += a2 * inv; t3 += a3 * inv;          \
  }

  DO_REL(kv_u, 0, ss_b, cNU)
  DO_REL(kv_t, (cNI + 1), ss_t, cNT)
  DO_REL(kv_i, 2 * (cNI + 1), ss_i, cNIM)
#undef DO_REL
#undef EDGE_DOT

  ushort4 o;
  o.x = f2bf(gelu_f(t0));
  o.y = f2bf(gelu_f(t1));
  o.z = f2bf(gelu_f(t2));
  o.w = f2bf(gelu_f(t3));
  ((ushort4*)(gout + (size_t)item * 256))[lane] = o;
}

}  // namespace

extern "C" void kernel_launch(void* const* d_in, const int* in_sizes, int n_in,
                              void* d_out, int out_size, void* d_ws, size_t ws_size,
                              hipStream_t stream) {
  (void)in_sizes; (void)n_in; (void)out_size; (void)ws_size;
  const float* x_user  = (const float*)d_in[0];
  const float* x_item  = (const float*)d_in[1];
  const float* x_taste = (const float*)d_in[2];
  const float* x_image = (const float*)d_in[3];
  const int* eb_src  = (const int*)d_in[4];
  const int* eb_dst  = (const int*)d_in[5];
  const int* eta_src = (const int*)d_in[6];
  const int* eta_dst = (const int*)d_in[7];
  const int* eia_src = (const int*)d_in[8];
  const int* eia_dst = (const int*)d_in[9];
  const float* Wk_u = (const float*)d_in[10];
  const float* bk_u = (const float*)d_in[11];
  const float* Wv_u = (const float*)d_in[12];
  const float* bv_u = (const float*)d_in[13];
  const float* Wk_t = (const float*)d_in[14];
  const float* bk_t = (const float*)d_in[15];
  const float* Wv_t = (const float*)d_in[16];
  const float* bv_t = (const float*)d_in[17];
  const float* Wk_i = (const float*)d_in[18];
  const float* bk_i = (const float*)d_in[19];
  const float* Wv_i = (const float*)d_in[20];
  const float* bv_i = (const float*)d_in[21];
  const float* Wq   = (const float*)d_in[22];
  const float* bq   = (const float*)d_in[23];
  const float* a_b  = (const float*)d_in[24];
  const float* m_b  = (const float*)d_in[25];
  const float* p_b  = (const float*)d_in[26];
  const float* a_t  = (const float*)d_in[27];
  const float* m_t  = (const float*)d_in[28];
  const float* p_t  = (const float*)d_in[29];
  const float* a_i  = (const float*)d_in[30];
  const float* m_i  = (const float*)d_in[31];
  const float* p_i  = (const float*)d_in[32];
  const float* Wo   = (const float*)d_in[33];
  const float* bo   = (const float*)d_in[34];
  const float* skip = (const float*)d_in[35];

  char* p = (char*)d_ws;
  auto alloc = [&](size_t n) -> char* {
    char* r = p;
    p += (n + 255) & ~(size_t)255;
    return r;
  };
  unsigned short* q      = (unsigned short*)alloc((size_t)cNI * 256 * 2);
  unsigned short* kv_u   = (unsigned short*)alloc((size_t)cNU * 512 * 2);
  unsigned short* kv_t   = (unsigned short*)alloc((size_t)cNT * 512 * 2);
  unsigned short* kv_i   = (unsigned short*)alloc((size_t)cNIM * 512 * 2);
  unsigned short* gagg   = (unsigned short*)alloc((size_t)cNI * 256 * 2);
  unsigned short* WkvT_u = (unsigned short*)alloc(512 * 256 * 2);
  unsigned short* WkvT_t = (unsigned short*)alloc(512 * 256 * 2);
  unsigned short* WkvT_i = (unsigned short*)alloc(512 * 256 * 2);
  unsigned short* WqT    = (unsigned short*)alloc(256 * 256 * 2);
  unsigned short* WoT    = (unsigned short*)alloc(256 * 256 * 2);
  float* bkv_u = (float*)alloc(512 * 4);
  float* bkv_t = (float*)alloc(512 * 4);
  float* bkv_i = (float*)alloc(512 * 4);
  float* bqf   = (float*)alloc(256 * 4);
  float* bof   = (float*)alloc(256 * 4);
  int* cnt   = (int*)alloc((size_t)cTOT * 4);
  int* off   = (int*)alloc((size_t)3 * (cNI + 1) * 4);
  int* cur   = (int*)alloc((size_t)cTOT * 4);
  int* tpre  = (int*)alloc((size_t)cSCANB * 256 * 4);
  int* bsum  = (int*)alloc(64 * 4);
  int* ss_b = (int*)alloc((size_t)cEB * 4);
  int* ss_t = (int*)alloc((size_t)cETA * 4);
  int* ss_i = (int*)alloc((size_t)cEIA * 4);

  hipMemsetAsync(cnt, 0, (size_t)cTOT * 4, stream);

  combine_kernel<<<2048, 256, 0, stream>>>(
      Wk_u, bk_u, Wv_u, bv_u, Wk_t, bk_t, Wv_t, bv_t, Wk_i, bk_i, Wv_i, bv_i,
      a_b, m_b, p_b, a_t, m_t, p_t, a_i, m_i, p_i,
      Wq, bq, Wo, bo,
      WkvT_u, bkv_u, WkvT_t, bkv_t, WkvT_i, bkv_i, WqT, bqf, WoT, bof);

  // fused projection GEMMs: q | kv_u | kv_t | kv_i  (2659 strips)
  gemm_strip_kernel<0><<<cSQ + cSU + cST + cSIM, 256, 0, stream>>>(
      x_item,  WqT,    bqf,   q,    cNI,  256,
      x_user,  WkvT_u, bkv_u, kv_u, cNU,  512,
      x_taste, WkvT_t, bkv_t, kv_t, cNT,  512,
      x_image, WkvT_i, bkv_i, kv_i, cNIM, 512,
      nullptr, nullptr);

  hist_kernel<<<1563, 256, 0, stream>>>(eb_dst, eta_dst, eia_dst, cnt);
  scan1_kernel<<<cSCANB, 256, 0, stream>>>(cnt, tpre, bsum);
  scan3_kernel<<<cSCANB, 256, 0, stream>>>(cnt, tpre, bsum, off, cur);
  scatter_kernel<<<1563, 256, 0, stream>>>(eb_src, eb_dst, eta_src, eta_dst, eia_src, eia_dst,
                                           cur, ss_b, ss_t, ss_i);

  attend_kernel<<<12500, 256, 0, stream>>>(q, kv_u, kv_t, kv_i, off, ss_b, ss_t, ss_i, gagg);

  // final GEMM: A = gelu'd agg (bf16), epilogue does skip-blend + residual
  gemm_strip_kernel<1><<<cSQ, 256, 0, stream>>>(
      gagg, WoT, bof, d_out, cNI, 256,
      nullptr, nullptr, nullptr, nullptr, 0, 0,
      nullptr, nullptr, nullptr, nullptr, 0, 0,
      nullptr, nullptr, nullptr, nullptr, 0, 0,
      x_item, skip);
}